// Round 12
// baseline (383.166 us; speedup 1.0000x reference)
//
#include <hip/hip_runtime.h>
#include <cfloat>
#include <cmath>

static constexpr int NN   = 10000;
static constexpr int NE   = 160000;
static constexpr int NA   = 8;
static constexpr int D1   = 512;
static constexpr int EMBD = 128;
static constexpr int NATTR= 64;
static constexpr int OUTD = 64;
static constexpr int NFR  = 1500;
static constexpr int AGG_NB = 250;

typedef short bf16x8 __attribute__((ext_vector_type(8)));
typedef float f32x4  __attribute__((ext_vector_type(4)));

__device__ __forceinline__ float b2f(unsigned short u) {
    union { unsigned u; float f; } v; v.u = ((unsigned)u) << 16; return v.f;
}
__device__ __forceinline__ unsigned short f2b(float f) {
    union { float f; unsigned u; } v; v.f = f;
    unsigned r = v.u + 0x7FFFu + ((v.u >> 16) & 1u);
    return (unsigned short)(r >> 16);
}
__device__ __forceinline__ float lrelu(float z) { return (z > 0.f) ? z : 0.2f * z; }

// ================= fused prep: attr_ee | gather | indeg | seed =================
__global__ __launch_bounds__(512) void k_prep(const float* __restrict__ pred_emb,
                                              const float* __restrict__ We1,
                                              const float* __restrict__ We2,
                                              const int* __restrict__ node_pred,
                                              const int* __restrict__ e_dst,
                                              const int* __restrict__ arg_nodes,
                                              unsigned short* __restrict__ attr1,
                                              unsigned short* __restrict__ attr2,
                                              unsigned short* __restrict__ pemb,
                                              int* __restrict__ counts,
                                              unsigned* __restrict__ maskA) {
    int b = blockIdx.x, t = threadIdx.x;
    if (b < 128) {                       // attr tables
        int a = b & 63;
        const float* We = (b >> 6) ? We2 : We1;
        unsigned short* out = (b >> 6) ? attr2 : attr1;
        __shared__ float row[EMBD];
        if (t < EMBD) row[t] = pred_emb[a * EMBD + t];
        __syncthreads();
        float acc = 0.f;
        for (int k = 0; k < EMBD; ++k) acc += row[k] * We[k * D1 + t];
        out[a * D1 + t] = f2b(acc);
    } else if (b < 753) {                // gather pemb (320000 float4)
        int idx = (b - 128) * 512 + t;
        int n = idx >> 5, j = idx & 31;
        float4 v = ((const float4*)(pred_emb + (size_t)node_pred[n] * EMBD))[j];
        ushort4 o; o.x = f2b(v.x); o.y = f2b(v.y); o.z = f2b(v.z); o.w = f2b(v.w);
        ((ushort4*)(pemb + (size_t)n * EMBD))[j] = o;
    } else if (b < 853) {                // in-degree
        int id = (b - 753) * 512 + t;
        for (int e = id; e < NE; e += 100 * 512) atomicAdd(&counts[e_dst[e]], 1);
    } else {                             // seed masks
        if (t < NA) atomicOr(&maskA[arg_nodes[t]], 1u << t);
    }
}

// ================= transpose+cast the 4 weight matrices (out: [N][K] bf16) =================
__global__ __launch_bounds__(256) void k_transp(const float* __restrict__ W1, const float* __restrict__ W2,
                                                const float* __restrict__ W3, const float* __restrict__ W4,
                                                unsigned short* __restrict__ o1, unsigned short* __restrict__ o2,
                                                unsigned short* __restrict__ o3, unsigned short* __restrict__ o4) {
    int b = blockIdx.x;
    const float* W; unsigned short* out; int Kd, tile;
    if (b < 16)      { W = W1; out = o1; Kd = 128; tile = b; }
    else if (b < 32) { W = W2; out = o2; Kd = 128; tile = b - 16; }
    else if (b < 96) { W = W3; out = o3; Kd = 512; tile = b - 32; }
    else             { W = W4; out = o4; Kd = 512; tile = b - 96; }
    int nrt = Kd / 64;
    int rt = tile % nrt, ct = tile / nrt;
    int r0 = rt * 64, c0 = ct * 64;
    __shared__ float tl[64][65];
    int tid = threadIdx.x;
#pragma unroll
    for (int i = 0; i < 16; ++i) {
        int idx = tid + 256 * i;
        int row = idx >> 6, col = idx & 63;
        tl[row][col] = W[(size_t)(r0 + row) * D1 + c0 + col];
    }
    __syncthreads();
#pragma unroll
    for (int i = 0; i < 16; ++i) {
        int idx = tid + 256 * i;
        int orow = idx >> 6, ocol = idx & 63;
        out[(size_t)(c0 + orow) * Kd + r0 + ocol] = f2b(tl[ocol][orow]);
    }
}

// ================= generic single-block scan (2 barriers) =================
template <int CE>
__global__ __launch_bounds__(1024) void k_scan_g(const int* __restrict__ counts, int n,
                                                 int* __restrict__ row_ptr,
                                                 int* __restrict__ cursor) {
    __shared__ int wsum[16];
    __shared__ int total_s;
    int t = threadIdx.x, lane = t & 63, w = t >> 6;
    int base = t * CE;
    int v[CE];
    int s = 0;
#pragma unroll
    for (int j = 0; j < CE; ++j) {
        int idx = base + j;
        int x = (idx < n) ? counts[idx] : 0;
        v[j] = s; s += x;
    }
    int inc = s;
#pragma unroll
    for (int off = 1; off < 64; off <<= 1) {
        int u = __shfl_up(inc, off, 64);
        if (lane >= off) inc += u;
    }
    if (lane == 63) wsum[w] = inc;
    __syncthreads();
    if (w == 0 && lane < 16) {
        int ws = wsum[lane];
        int wi = ws;
#pragma unroll
        for (int off = 1; off < 16; off <<= 1) {
            int u = __shfl_up(wi, off, 64);
            if (lane >= off) wi += u;
        }
        wsum[lane] = wi - ws;
        if (lane == 15) total_s = wi;
    }
    __syncthreads();
    int excl = wsum[w] + (inc - s);
#pragma unroll
    for (int j = 0; j < CE; ++j) {
        int idx = base + j;
        if (idx < n) { int val = excl + v[j]; row_ptr[idx] = val; cursor[idx] = val; }
    }
    if (t == 0) row_ptr[n] = total_s;
}

// ================= scatter main CSR (packed src|attr<<14) =================
__global__ void k_scatter(const int* __restrict__ src, const int* __restrict__ dst,
                          const int* __restrict__ attr, int* __restrict__ cursor,
                          int* __restrict__ csr_pack) {
    int stride = gridDim.x * blockDim.x;
    for (int e = blockIdx.x * blockDim.x + threadIdx.x; e < NE; e += stride) {
        int pos = atomicAdd(&cursor[dst[e]], 1);
        csr_pack[pos] = src[e] | ((attr[e] & 63) << 14);
    }
}

// ================= k-hop propagation =================
__global__ void k_prop(const unsigned* __restrict__ oldm, unsigned* __restrict__ newm,
                       const int* __restrict__ src, const int* __restrict__ dst) {
    int stride = gridDim.x * blockDim.x;
    int t0 = blockIdx.x * blockDim.x + threadIdx.x;
    for (int n = t0; n < NN; n += stride) atomicOr(&newm[n], oldm[n]);
    for (int e = t0; e < NE; e += stride) {
        unsigned v = oldm[dst[e]];
        if (v) atomicOr(&newm[src[e]], v);
    }
}

// ================= attr histogram =================
__global__ void k_hist(const int* __restrict__ src, const int* __restrict__ dst,
                       const int* __restrict__ attr, const unsigned* __restrict__ mask,
                       unsigned* __restrict__ hist) {
    __shared__ unsigned lh[9 * 64];
    for (int i = threadIdx.x; i < 9 * 64; i += blockDim.x) lh[i] = 0;
    __syncthreads();
    int stride = gridDim.x * blockDim.x;
    for (int e = blockIdx.x * blockDim.x + threadIdx.x; e < NE; e += stride) {
        int a = attr[e] & 63;
        atomicAdd(&lh[a], 1u);
        unsigned bits = mask[src[e]] & mask[dst[e]];
        while (bits) {
            int i = __ffs(bits) - 1;
            bits &= bits - 1;
            atomicAdd(&lh[(1 + i) * 64 + a], 1u);
        }
    }
    __syncthreads();
    for (int i = threadIdx.x; i < 9 * 64; i += blockDim.x)
        if (lh[i]) atomicAdd(&hist[i], lh[i]);
}

// ================= mean edge embedding tables =================
__global__ __launch_bounds__(512) void k_mean_ee(const unsigned* __restrict__ hist,
                                                 const float* __restrict__ pred_emb,
                                                 const float* __restrict__ We1,
                                                 const float* __restrict__ We2,
                                                 unsigned short* __restrict__ mee1,
                                                 unsigned short* __restrict__ mee2) {
    int g = blockIdx.x;
    const float* We = (g == 0) ? We1 : We2;
    unsigned short* out = (g == 0) ? mee1 : (mee2 + (g - 1) * D1);
    __shared__ float cnt[64];
    __shared__ float me[EMBD];
    __shared__ float tot_s;
    if (threadIdx.x < 64) cnt[threadIdx.x] = (float)hist[g * 64 + threadIdx.x];
    __syncthreads();
    if (threadIdx.x == 0) {
        float tt = 0.f;
        for (int a = 0; a < 64; ++a) tt += cnt[a];
        tot_s = fmaxf(tt, 1.0f);
    }
    __syncthreads();
    if (threadIdx.x < EMBD) {
        float acc = 0.f;
        for (int a = 0; a < 64; ++a) acc += cnt[a] * pred_emb[a * EMBD + threadIdx.x];
        me[threadIdx.x] = acc / tot_s;
    }
    __syncthreads();
    int c = threadIdx.x;
    float acc = 0.f;
    for (int k = 0; k < EMBD; ++k) acc += me[k] * We[k * D1 + c];
    out[c] = f2b(acc);
}

// ===== fused dual-B bf16 MFMA GEMM: one A-stage, both C0/C1. 64x64 tile, BK=64, XOR swizzle =====
__global__ __launch_bounds__(256) void k_gemm_dual(const unsigned short* __restrict__ A,
                                                   const unsigned short* __restrict__ BT0,
                                                   const unsigned short* __restrict__ BT1,
                                                   unsigned short* __restrict__ C0,
                                                   unsigned short* __restrict__ C1,
                                                   int M, int K, int N) {
    __shared__ unsigned short As[64 * 64];
    __shared__ unsigned short Bs0[64 * 64];
    __shared__ unsigned short Bs1[64 * 64];
    int tid = threadIdx.x;
    int wave = tid >> 6, lane = tid & 63;
    int bm = blockIdx.y * 64, bn = blockIdx.x * 64;
    int wr = (wave >> 1) * 32, wc = (wave & 1) * 32;
    int r = lane & 15, s8 = (lane >> 4) * 8;
    int rx = (r & 7) << 3;
    f32x4 zero = {0.f, 0.f, 0.f, 0.f};
    f32x4 acc0[2][2] = {{zero, zero}, {zero, zero}};
    f32x4 acc1[2][2] = {{zero, zero}, {zero, zero}};
    for (int k0 = 0; k0 < K; k0 += 64) {
#pragma unroll
        for (int i = 0; i < 8; ++i) {
            int idx = tid + 256 * i;
            int row = idx >> 5, cdw = idx & 31;
            int col = (cdw * 2) ^ ((row & 7) << 3);
            unsigned va = 0;
            if (bm + row < M) va = *(const unsigned*)&A[(size_t)(bm + row) * K + k0 + cdw * 2];
            *(unsigned*)&As[row * 64 + col] = va;
            unsigned vb0 = *(const unsigned*)&BT0[(size_t)(bn + row) * K + k0 + cdw * 2];
            *(unsigned*)&Bs0[row * 64 + col] = vb0;
            unsigned vb1 = *(const unsigned*)&BT1[(size_t)(bn + row) * K + k0 + cdw * 2];
            *(unsigned*)&Bs1[row * 64 + col] = vb1;
        }
        __syncthreads();
#pragma unroll
        for (int kk = 0; kk < 2; ++kk) {
            int csw = (kk * 32 + s8) ^ rx;
            bf16x8 a0 = *(const bf16x8*)&As[(wr + r) * 64 + csw];
            bf16x8 a1 = *(const bf16x8*)&As[(wr + 16 + r) * 64 + csw];
            bf16x8 p0 = *(const bf16x8*)&Bs0[(wc + r) * 64 + csw];
            bf16x8 p1 = *(const bf16x8*)&Bs0[(wc + 16 + r) * 64 + csw];
            bf16x8 q0 = *(const bf16x8*)&Bs1[(wc + r) * 64 + csw];
            bf16x8 q1 = *(const bf16x8*)&Bs1[(wc + 16 + r) * 64 + csw];
            acc0[0][0] = __builtin_amdgcn_mfma_f32_16x16x32_bf16(a0, p0, acc0[0][0], 0, 0, 0);
            acc0[0][1] = __builtin_amdgcn_mfma_f32_16x16x32_bf16(a0, p1, acc0[0][1], 0, 0, 0);
            acc0[1][0] = __builtin_amdgcn_mfma_f32_16x16x32_bf16(a1, p0, acc0[1][0], 0, 0, 0);
            acc0[1][1] = __builtin_amdgcn_mfma_f32_16x16x32_bf16(a1, p1, acc0[1][1], 0, 0, 0);
            acc1[0][0] = __builtin_amdgcn_mfma_f32_16x16x32_bf16(a0, q0, acc1[0][0], 0, 0, 0);
            acc1[0][1] = __builtin_amdgcn_mfma_f32_16x16x32_bf16(a0, q1, acc1[0][1], 0, 0, 0);
            acc1[1][0] = __builtin_amdgcn_mfma_f32_16x16x32_bf16(a1, q0, acc1[1][0], 0, 0, 0);
            acc1[1][1] = __builtin_amdgcn_mfma_f32_16x16x32_bf16(a1, q1, acc1[1][1], 0, 0, 0);
        }
        __syncthreads();
    }
    int cr = (lane >> 4) * 4, cc = lane & 15;
#pragma unroll
    for (int i = 0; i < 2; ++i)
#pragma unroll
        for (int j = 0; j < 2; ++j)
#pragma unroll
            for (int q = 0; q < 4; ++q) {
                int row = bm + wr + i * 16 + cr + q;
                int col = bn + wc + j * 16 + cc;
                if (row < M) {
                    C0[(size_t)row * N + col] = f2b(acc0[i][j][q]);
                    C1[(size_t)row * N + col] = f2b(acc1[i][j][q]);
                }
            }
}

// ===== full GATv2: 16-lane groups, 8ch/lane via uint4, 4 edges/wave-iter =====
__global__ __launch_bounds__(256) void k_gat(const unsigned short* __restrict__ xl,
                                             const unsigned short* __restrict__ xr,
                                             const unsigned short* __restrict__ attr_ee,
                                             const unsigned short* __restrict__ mean_ee,
                                             const float* __restrict__ att,
                                             const float* __restrict__ bias,
                                             const int* __restrict__ row_ptr,
                                             const int* __restrict__ csr_pack,
                                             unsigned short* __restrict__ out) {
    int n = blockIdx.x;
    int t = threadIdx.x;
    int lane = t & 63;
    int g = lane >> 4;
    int li = lane & 15;
    int c = (t >> 6) * 128 + li * 8;
    uint4 vr4 = *(const uint4*)&xr[(size_t)n * D1 + c];
    float xrv[8];
    { unsigned w0 = vr4.x, w1 = vr4.y, w2 = vr4.z, w3 = vr4.w;
      xrv[0] = b2f((unsigned short)(w0 & 0xffff)); xrv[1] = b2f((unsigned short)(w0 >> 16));
      xrv[2] = b2f((unsigned short)(w1 & 0xffff)); xrv[3] = b2f((unsigned short)(w1 >> 16));
      xrv[4] = b2f((unsigned short)(w2 & 0xffff)); xrv[5] = b2f((unsigned short)(w2 >> 16));
      xrv[6] = b2f((unsigned short)(w3 & 0xffff)); xrv[7] = b2f((unsigned short)(w3 >> 16)); }
    float4 aLo = *(const float4*)&att[c];
    float4 aHi = *(const float4*)&att[c + 4];
    float av[8] = {aLo.x, aLo.y, aLo.z, aLo.w, aHi.x, aHi.y, aHi.z, aHi.w};
    float m = -FLT_MAX, den = 0.f;
    float ac[8] = {0.f, 0.f, 0.f, 0.f, 0.f, 0.f, 0.f, 0.f};
    int pstart = row_ptr[n], pend = row_ptr[n + 1];
    int deg = pend - pstart;
    int items = deg + 1;
    for (int it = 0; it < items; it += 4) {
        int idx = it + g;
        bool valid = idx < items;
        int s; const unsigned short* ee;
        if (!valid || idx == deg) { s = n; ee = mean_ee; }
        else {
            int v = csr_pack[pstart + idx];
            s = v & 0x3FFF;
            ee = attr_ee + (size_t)((v >> 14) & 63) * D1;
        }
        uint4 vs = *(const uint4*)&xl[(size_t)s * D1 + c];
        uint4 ve = *(const uint4*)&ee[c];
        float x[8];
        x[0] = b2f((unsigned short)(vs.x & 0xffff)); x[1] = b2f((unsigned short)(vs.x >> 16));
        x[2] = b2f((unsigned short)(vs.y & 0xffff)); x[3] = b2f((unsigned short)(vs.y >> 16));
        x[4] = b2f((unsigned short)(vs.z & 0xffff)); x[5] = b2f((unsigned short)(vs.z >> 16));
        x[6] = b2f((unsigned short)(vs.w & 0xffff)); x[7] = b2f((unsigned short)(vs.w >> 16));
        float e[8];
        e[0] = b2f((unsigned short)(ve.x & 0xffff)); e[1] = b2f((unsigned short)(ve.x >> 16));
        e[2] = b2f((unsigned short)(ve.y & 0xffff)); e[3] = b2f((unsigned short)(ve.y >> 16));
        e[4] = b2f((unsigned short)(ve.z & 0xffff)); e[5] = b2f((unsigned short)(ve.z >> 16));
        e[6] = b2f((unsigned short)(ve.w & 0xffff)); e[7] = b2f((unsigned short)(ve.w >> 16));
        float ps = 0.f;
#pragma unroll
        for (int j = 0; j < 8; ++j) ps += lrelu(x[j] + xrv[j] + e[j]) * av[j];
#pragma unroll
        for (int off = 1; off < 16; off <<= 1) ps += __shfl_xor(ps, off, 64);
        if (!valid) ps = -FLT_MAX;
        float nm = fmaxf(m, ps);
        float sc = __expf(m - nm);
        float w  = __expf(ps - nm);
        den = den * sc + w;
#pragma unroll
        for (int j = 0; j < 8; ++j) ac[j] = ac[j] * sc + w * x[j];
        m = nm;
    }
#pragma unroll
    for (int off = 16; off <= 32; off <<= 1) {
        float mO = __shfl_xor(m, off, 64);
        float dO = __shfl_xor(den, off, 64);
        float aO[8];
#pragma unroll
        for (int j = 0; j < 8; ++j) aO[j] = __shfl_xor(ac[j], off, 64);
        float nm = fmaxf(m, mO);
        float sa = __expf(m - nm), sb = __expf(mO - nm);
        den = den * sa + dO * sb;
#pragma unroll
        for (int j = 0; j < 8; ++j) ac[j] = ac[j] * sa + aO[j] * sb;
        m = nm;
    }
    if (g == 0) {
        float inv = 1.f / (den + 1e-16f);
        float4 bLo = *(const float4*)&bias[c];
        float4 bHi = *(const float4*)&bias[c + 4];
        float bv[8] = {bLo.x, bLo.y, bLo.z, bLo.w, bHi.x, bHi.y, bHi.z, bHi.w};
        unsigned short q[8];
#pragma unroll
        for (int j = 0; j < 8; ++j) q[j] = f2b(ac[j] * inv + bv[j]);
        uint4 o;
        o.x = ((unsigned)q[1] << 16) | q[0];
        o.y = ((unsigned)q[3] << 16) | q[2];
        o.z = ((unsigned)q[5] << 16) | q[4];
        o.w = ((unsigned)q[7] << 16) | q[6];
        *(uint4*)&out[(size_t)n * D1 + c] = o;
    }
}

// ================= merged 4-bit masked GATv2 (ballot compaction) =================
__global__ __launch_bounds__(256) void k_gat_m4(const unsigned short* __restrict__ xl,
                                                const unsigned short* __restrict__ xr,
                                                const unsigned short* __restrict__ attr_ee,
                                                const unsigned short* __restrict__ mee,
                                                const float* __restrict__ att,
                                                const float* __restrict__ bias,
                                                const int* __restrict__ row_ptr,
                                                const int* __restrict__ csr_pack,
                                                const unsigned* __restrict__ mask, int bitbase,
                                                unsigned short* __restrict__ o0,
                                                unsigned short* __restrict__ o1,
                                                unsigned short* __restrict__ o2,
                                                unsigned short* __restrict__ o3) {
    int n = blockIdx.x;
    unsigned mb_n = (mask[n] >> bitbase) & 0xFu;
    if (!mb_n) return;
    __shared__ int lst[256];
    __shared__ int lcnt;
    int t = threadIdx.x, lane = t & 63;
    int c = 2 * t;
    unsigned vr_ = *(const unsigned*)&xr[(size_t)n * D1 + c];
    float xr0 = b2f((unsigned short)(vr_ & 0xffff));
    float xr1 = b2f((unsigned short)(vr_ >> 16));
    float a0 = att[c], a1 = att[c + 1];
    float m[4], den[4], ac0[4], ac1[4];
#pragma unroll
    for (int b = 0; b < 4; ++b) { m[b] = -FLT_MAX; den[b] = 0.f; ac0[b] = 0.f; ac1[b] = 0.f; }
    int pstart = row_ptr[n], pend = row_ptr[n + 1];
    for (int p0 = pstart; p0 < pend; p0 += 256) {
        int chunk = min(256, pend - p0);
        __syncthreads();
        if (t == 0) lcnt = 0;
        __syncthreads();
        unsigned bits = 0; int pk = 0;
        if (t < chunk) {
            pk = csr_pack[p0 + t];
            bits = (mask[pk & 0x3FFF] >> bitbase) & mb_n & 0xFu;
        }
        bool kept = bits != 0;
        unsigned long long bal = __ballot(kept);
        int base = 0;
        if (lane == 0) base = atomicAdd(&lcnt, __popcll(bal));
        base = __shfl(base, 0, 64);
        int pfx = __popcll(bal & ((1ull << lane) - 1));
        if (kept) lst[base + pfx] = (pk & 0xFFFFF) | ((int)bits << 20);
        __syncthreads();
        int cnt = lcnt;
        int i = 0;
        for (; i + 1 < cnt; i += 2) {
            int vA = lst[i], vB = lst[i + 1];
            int sA = vA & 0x3FFF, sB = vB & 0x3FFF;
            unsigned bA = ((unsigned)vA >> 20) & 0xF, bB = ((unsigned)vB >> 20) & 0xF;
            const unsigned short* eA = attr_ee + (size_t)((vA >> 14) & 63) * D1;
            const unsigned short* eB = attr_ee + (size_t)((vB >> 14) & 63) * D1;
            unsigned vsA = *(const unsigned*)&xl[(size_t)sA * D1 + c];
            unsigned veA = *(const unsigned*)&eA[c];
            unsigned vsB = *(const unsigned*)&xl[(size_t)sB * D1 + c];
            unsigned veB = *(const unsigned*)&eB[c];
            float xA0 = b2f((unsigned short)(vsA & 0xffff)), xA1 = b2f((unsigned short)(vsA >> 16));
            float xB0 = b2f((unsigned short)(vsB & 0xffff)), xB1 = b2f((unsigned short)(vsB >> 16));
            float zA0 = lrelu(xA0 + xr0 + b2f((unsigned short)(veA & 0xffff)));
            float zA1 = lrelu(xA1 + xr1 + b2f((unsigned short)(veA >> 16)));
            float zB0 = lrelu(xB0 + xr0 + b2f((unsigned short)(veB & 0xffff)));
            float zB1 = lrelu(xB1 + xr1 + b2f((unsigned short)(veB >> 16)));
            float pa = zA0 * a0 + zA1 * a1;
            float pb = zB0 * a0 + zB1 * a1;
#pragma unroll
            for (int off = 32; off; off >>= 1) {
                pa += __shfl_xor(pa, off, 64);
                pb += __shfl_xor(pb, off, 64);
            }
#pragma unroll
            for (int b = 0; b < 4; ++b) {
                if (!(((bA | bB) >> b) & 1)) continue;   // wave-uniform
                float pae = ((bA >> b) & 1) ? pa : -FLT_MAX;
                float pbe = ((bB >> b) & 1) ? pb : -FLT_MAX;
                float nm = fmaxf(m[b], fmaxf(pae, pbe));
                float sc = __expf(m[b] - nm);
                float wa = __expf(pae - nm);
                float wb = __expf(pbe - nm);
                den[b] = den[b] * sc + wa + wb;
                ac0[b] = ac0[b] * sc + wa * xA0 + wb * xB0;
                ac1[b] = ac1[b] * sc + wa * xA1 + wb * xB1;
                m[b] = nm;
            }
        }
        if (i < cnt) {
            int vA = lst[i];
            int sA = vA & 0x3FFF;
            unsigned bA = ((unsigned)vA >> 20) & 0xF;
            const unsigned short* eA = attr_ee + (size_t)((vA >> 14) & 63) * D1;
            unsigned vsA = *(const unsigned*)&xl[(size_t)sA * D1 + c];
            unsigned veA = *(const unsigned*)&eA[c];
            float xA0 = b2f((unsigned short)(vsA & 0xffff)), xA1 = b2f((unsigned short)(vsA >> 16));
            float zA0 = lrelu(xA0 + xr0 + b2f((unsigned short)(veA & 0xffff)));
            float zA1 = lrelu(xA1 + xr1 + b2f((unsigned short)(veA >> 16)));
            float pa = zA0 * a0 + zA1 * a1;
#pragma unroll
            for (int off = 32; off; off >>= 1) pa += __shfl_xor(pa, off, 64);
#pragma unroll
            for (int b = 0; b < 4; ++b) {
                if (!((bA >> b) & 1)) continue;
                float nm = fmaxf(m[b], pa);
                float sc = __expf(m[b] - nm);
                float wa = __expf(pa - nm);
                den[b] = den[b] * sc + wa;
                ac0[b] = ac0[b] * sc + wa * xA0;
                ac1[b] = ac1[b] * sc + wa * xA1;
                m[b] = nm;
            }
        }
    }
    unsigned vsn = *(const unsigned*)&xl[(size_t)n * D1 + c];
    float xn0 = b2f((unsigned short)(vsn & 0xffff)), xn1 = b2f((unsigned short)(vsn >> 16));
    float bi0 = bias[c], bi1 = bias[c + 1];
#pragma unroll
    for (int b = 0; b < 4; ++b) {
        if (!((mb_n >> b) & 1)) continue;
        unsigned ve = *(const unsigned*)&mee[(size_t)b * D1 + c];
        float z0 = lrelu(xn0 + xr0 + b2f((unsigned short)(ve & 0xffff)));
        float z1 = lrelu(xn1 + xr1 + b2f((unsigned short)(ve >> 16)));
        float ps = z0 * a0 + z1 * a1;
#pragma unroll
        for (int off = 32; off; off >>= 1) ps += __shfl_xor(ps, off, 64);
        float nm = fmaxf(m[b], ps);
        float sc = __expf(m[b] - nm);
        float w  = __expf(ps - nm);
        float dd = den[b] * sc + w;
        float A0 = ac0[b] * sc + w * xn0;
        float A1 = ac1[b] * sc + w * xn1;
        float inv = 1.f / (dd + 1e-16f);
        unsigned short q0 = f2b(A0 * inv + bi0);
        unsigned short q1 = f2b(A1 * inv + bi1);
        unsigned pkd = ((unsigned)q1 << 16) | q0;
        unsigned short* ob = (b == 0) ? o0 : (b == 1) ? o1 : (b == 2) ? o2 : o3;
        *(unsigned*)&ob[(size_t)n * D1 + c] = pkd;
    }
}

// ================= full column softmax-aggr partial (quad-ILP) =================
__global__ __launch_bounds__(512) void k_aggr_partial(const unsigned short* __restrict__ x,
                                                      float* __restrict__ part) {
    int c = threadIdx.x;
    int rows = NN / gridDim.x;
    int r0 = blockIdx.x * rows;
    int r1 = r0 + rows;
    float m = -FLT_MAX, den = 0.f, num = 0.f;
    for (int r = r0; r < r1; r += 4) {
        float v0 = b2f(x[(size_t)r * D1 + c]);
        float v1 = b2f(x[(size_t)(r + 1) * D1 + c]);
        float v2 = b2f(x[(size_t)(r + 2) * D1 + c]);
        float v3 = b2f(x[(size_t)(r + 3) * D1 + c]);
        float nm = fmaxf(fmaxf(fmaxf(v0, v1), fmaxf(v2, v3)), m);
        float sc = __expf(m - nm);
        float w0 = __expf(v0 - nm);
        float w1 = __expf(v1 - nm);
        float w2 = __expf(v2 - nm);
        float w3 = __expf(v3 - nm);
        den = den * sc + ((w0 + w1) + (w2 + w3));
        num = num * sc + ((w0 * v0 + w1 * v1) + (w2 * v2 + w3 * v3));
        m = nm;
    }
    part[(blockIdx.x * 3 + 0) * D1 + c] = m;
    part[(blockIdx.x * 3 + 1) * D1 + c] = den;
    part[(blockIdx.x * 3 + 2) * D1 + c] = num;
}

// ================= merged 4-bit masked softmax-aggr partial =================
__global__ __launch_bounds__(512) void k_aggr_partial4(const unsigned short* __restrict__ h0,
                                                       const unsigned short* __restrict__ h1,
                                                       const unsigned short* __restrict__ h2,
                                                       const unsigned short* __restrict__ h3,
                                                       const unsigned* __restrict__ mask, int bitbase,
                                                       float* __restrict__ part) {
    int c = threadIdx.x;
    int rows = NN / gridDim.x;
    int r0 = blockIdx.x * rows;
    int r1 = r0 + rows;
    float m[4], den[4], num[4];
#pragma unroll
    for (int b = 0; b < 4; ++b) { m[b] = -FLT_MAX; den[b] = 0.f; num[b] = 0.f; }
    for (int r = r0; r < r1; ++r) {
        unsigned bits = (mask[r] >> bitbase) & 0xFu;
        if (!bits) continue;
#pragma unroll
        for (int b = 0; b < 4; ++b) {
            if (!((bits >> b) & 1)) continue;
            const unsigned short* hb = (b == 0) ? h0 : (b == 1) ? h1 : (b == 2) ? h2 : h3;
            float v = b2f(hb[(size_t)r * D1 + c]);
            float nm = fmaxf(m[b], v);
            float sc = __expf(m[b] - nm);
            float w  = __expf(v - nm);
            den[b] = den[b] * sc + w;
            num[b] = num[b] * sc + w * v;
            m[b] = nm;
        }
    }
#pragma unroll
    for (int b = 0; b < 4; ++b) {
        part[(((size_t)b * gridDim.x + blockIdx.x) * 3 + 0) * D1 + c] = m[b];
        part[(((size_t)b * gridDim.x + blockIdx.x) * 3 + 1) * D1 + c] = den[b];
        part[(((size_t)b * gridDim.x + blockIdx.x) * 3 + 2) * D1 + c] = num[b];
    }
}

// ================= wave-parallel combine =================
__global__ __launch_bounds__(512) void k_combine_w(const float* __restrict__ part,
                                                   int nb, int nset,
                                                   float* __restrict__ out) {
    int gw = (blockIdx.x * 512 + threadIdx.x) >> 6;
    int lane = threadIdx.x & 63;
    if (gw >= nset * D1) return;
    int s = gw >> 9;
    int c = gw & 511;
    const float* pp = part + (size_t)s * nb * 3 * D1;
    float m = -FLT_MAX;
    for (int k = lane; k < nb; k += 64) m = fmaxf(m, pp[(k * 3) * D1 + c]);
#pragma unroll
    for (int off = 32; off; off >>= 1) m = fmaxf(m, __shfl_xor(m, off, 64));
    float den = 0.f, num = 0.f;
    for (int k = lane; k < nb; k += 64) {
        float sc = __expf(pp[(k * 3 + 0) * D1 + c] - m);
        den += pp[(k * 3 + 1) * D1 + c] * sc;
        num += pp[(k * 3 + 2) * D1 + c] * sc;
    }
#pragma unroll
    for (int off = 32; off; off >>= 1) {
        den += __shfl_xor(den, off, 64);
        num += __shfl_xor(num, off, 64);
    }
    if (lane == 0) out[(size_t)s * D1 + c] = num / den;
}

// ================= HGT stage A =================
__global__ void k_hgt_a(const float* __restrict__ frame_x, const float* __restrict__ role_x,
                        const float* __restrict__ kqv_f, const float* __restrict__ kqvb_f,
                        const float* __restrict__ kqv_r, const float* __restrict__ kqvb_r,
                        float* __restrict__ kf, float* __restrict__ vf,
                        float* __restrict__ kr, float* __restrict__ qr, float* __restrict__ vr) {
    int b = blockIdx.x, j = threadIdx.x;
    const float *x, *W, *bi;
    float* out;
    if (b == 0)      { x = frame_x;               W = kqv_f;                    bi = kqvb_f;            out = kf; }
    else if (b == 1) { x = frame_x;               W = kqv_f + 2 * D1 * OUTD;    bi = kqvb_f + 2 * OUTD; out = vf; }
    else if (b < 10) { int i = b - 2;  x = role_x + i * D1; W = kqv_r;                 bi = kqvb_r;            out = kr + i * OUTD; }
    else if (b < 18) { int i = b - 10; x = role_x + i * D1; W = kqv_r + D1 * OUTD;     bi = kqvb_r + OUTD;     out = qr + i * OUTD; }
    else             { int i = b - 18; x = role_x + i * D1; W = kqv_r + 2 * D1 * OUTD; bi = kqvb_r + 2 * OUTD; out = vr + i * OUTD; }
    float acc = bi[j];
    for (int k = 0; k < D1; ++k) acc += x[k] * W[k * OUTD + j];
    out[j] = acc;
}

// ================= HGT stage B =================
__global__ __launch_bounds__(512) void k_hgt_b(const float* __restrict__ kf_g,
                                               const float* __restrict__ vf_g,
                                               const float* __restrict__ kr_g,
                                               const float* __restrict__ qr_g,
                                               const float* __restrict__ vr_g,
                                               const float* __restrict__ a_rel,
                                               const float* __restrict__ m_rel,
                                               const float* __restrict__ p_rel,
                                               const float* __restrict__ aW_f,
                                               const float* __restrict__ ab_f,
                                               const float* __restrict__ aW_r,
                                               const float* __restrict__ ab_r,
                                               float* __restrict__ out_f,
                                               float* __restrict__ out_r) {
    __shared__ float kf[64], vf[64], kr[512], qr[512], vr[512];
    __shared__ float ka1[64], vfm1[64], aggf[64], geluf[64];
    __shared__ float kra2[512], vrm[512], gelur[512];
    __shared__ float al[8][2];
    int t = threadIdx.x;
    if (t < 64) { kf[t] = kf_g[t]; vf[t] = vf_g[t]; }
    kr[t] = kr_g[t]; qr[t] = qr_g[t]; vr[t] = vr_g[t];
    __syncthreads();
    int i = t >> 6, j = t & 63;
    {
        float acc1 = 0.f, acc2 = 0.f;
        for (int k = 0; k < 64; ++k) {
            acc1 += kr[i * 64 + k] * a_rel[2 * 4096 + k * 64 + j];
            acc2 += vr[i * 64 + k] * m_rel[2 * 4096 + k * 64 + j];
        }
        kra2[t] = acc1; vrm[t] = acc2;
    }
    if (t < 64) {
        float acc1 = 0.f, acc2 = 0.f, acc3 = 0.f;
        for (int k = 0; k < 64; ++k) {
            acc1 += kf[k] * a_rel[1 * 4096 + k * 64 + j];
            acc2 += vf[k] * m_rel[0 * 4096 + k * 64 + j];
            acc3 += vf[k] * m_rel[1 * 4096 + k * 64 + j];
        }
        ka1[j] = acc1; aggf[j] = acc2; vfm1[j] = acc3;
    }
    __syncthreads();
    if (t < 8) {
        const float sq = 0.125f;
        float p1 = p_rel[1], p2 = p_rel[2];
        float sfr = 0.f, srr = 0.f;
        for (int d = 0; d < 64; ++d) {
            sfr += qr[t * 64 + d] * ka1[d];
            srr += qr[t * 64 + d] * kra2[t * 64 + d];
        }
        sfr *= sq * p1; srr *= sq * p2;
        float mx = fmaxf(sfr, srr);
        float e0 = __expf(sfr - mx), e1 = __expf(srr - mx);
        float inv = 1.f / (e0 + e1);
        al[t][0] = e0 * inv; al[t][1] = e1 * inv;
    }
    __syncthreads();
    {
        float av = al[i][0] * vfm1[j] + al[i][1] * vrm[t];
        gelur[t] = 0.5f * av * (1.f + erff(av * 0.70710678118654752f));
    }
    if (t < 64) geluf[t] = 0.5f * aggf[t] * (1.f + erff(aggf[t] * 0.70710678118654752f));
    __syncthreads();
    {
        float acc = ab_r[j];
        for (int k = 0; k < 64; ++k) acc += gelur[i * 64 + k] * aW_r[k * 64 + j];
        out_r[t] = acc;
    }
    if (t < 64) {
        float acc = ab_f[j];
        for (int k = 0; k < 64; ++k) acc += geluf[k] * aW_f[k * 64 + j];
        out_f[j] = acc;
    }
}

// ================= frame logits =================
__global__ void k_frame_logits(const float* __restrict__ out_f, const float* __restrict__ Wfr,
                               const float* __restrict__ bfr, float* __restrict__ flog) {
    __shared__ float xf[64];
    if (threadIdx.x < 64) xf[threadIdx.x] = out_f[threadIdx.x];
    __syncthreads();
    int j = blockIdx.x * blockDim.x + threadIdx.x;
    if (j >= NFR) return;
    float acc = bfr[j];
    for (int k = 0; k < 64; ++k) acc += xf[k] * Wfr[k * NFR + j];
    flog[j] = acc;
}

// ================= final: frame log_softmax + roles head =================
__global__ __launch_bounds__(512) void k_final(const float* __restrict__ flog,
                                               const float* __restrict__ out_r,
                                               const float* __restrict__ Wro,
                                               const float* __restrict__ bro,
                                               float* __restrict__ outp) {
    __shared__ float red[512];
    __shared__ float xr_s[512];
    int t = threadIdx.x;
    int i = t >> 6, j = t & 63;
    xr_s[t] = out_r[t];
    float racc = bro[j];
    for (int k = 0; k < 64; ++k) racc += xr_s[i * 64 + k] * Wro[k * 64 + j];
    float rm = racc;
#pragma unroll
    for (int off = 32; off; off >>= 1) rm = fmaxf(rm, __shfl_xor(rm, off, 64));
    float re = __expf(racc - rm);
    float rs = re;
#pragma unroll
    for (int off = 32; off; off >>= 1) rs += __shfl_xor(rs, off, 64);
    outp[NFR + t] = racc - rm - logf(rs);
    float m = -FLT_MAX;
    for (int q = t; q < NFR; q += 512) m = fmaxf(m, flog[q]);
    red[t] = m; __syncthreads();
    for (int off = 256; off; off >>= 1) { if (t < off) red[t] = fmaxf(red[t], red[t + off]); __syncthreads(); }
    float M = red[0]; __syncthreads();
    float s = 0.f;
    for (int q = t; q < NFR; q += 512) s += __expf(flog[q] - M);
    red[t] = s; __syncthreads();
    for (int off = 256; off; off >>= 1) { if (t < off) red[t] += red[t + off]; __syncthreads(); }
    float lse = M + logf(red[0]);
    for (int q = t; q < NFR; q += 512) outp[q] = flog[q] - lse;
}

// =====================================================================
extern "C" void kernel_launch(void* const* d_in, const int* in_sizes, int n_in,
                              void* d_out, int out_size, void* d_ws, size_t ws_size,
                              hipStream_t stream) {
    const int* node_pred  = (const int*)d_in[0];
    const int* edge_index = (const int*)d_in[1];
    const int* e_src = edge_index;
    const int* e_dst = edge_index + NE;
    const int* edge_attr  = (const int*)d_in[2];
    const int* arg_nodes  = (const int*)d_in[3];
    const float* pred_emb = (const float*)d_in[4];
    const float* Wl1 = (const float*)d_in[5];
    const float* Wr1 = (const float*)d_in[6];
    const float* We1 = (const float*)d_in[7];
    const float* att1 = (const float*)d_in[8];
    const float* b1  = (const float*)d_in[9];
    const float* Wl2 = (const float*)d_in[10];
    const float* Wr2 = (const float*)d_in[11];
    const float* We2 = (const float*)d_in[12];
    const float* att2 = (const float*)d_in[13];
    const float* b2  = (const float*)d_in[14];
    const float* kqv_f  = (const float*)d_in[15];
    const float* kqvb_f = (const float*)d_in[16];
    const float* kqv_r  = (const float*)d_in[17];
    const float* kqvb_r = (const float*)d_in[18];
    const float* a_rel  = (const float*)d_in[19];
    const float* m_rel  = (const float*)d_in[20];
    const float* p_rel  = (const float*)d_in[21];
    const float* aW_f = (const float*)d_in[22];
    const float* ab_f = (const float*)d_in[23];
    const float* aW_r = (const float*)d_in[24];
    const float* ab_r = (const float*)d_in[25];
    const float* Wfr = (const float*)d_in[26];
    const float* bfr = (const float*)d_in[27];
    const float* Wro = (const float*)d_in[28];
    const float* bro = (const float*)d_in[29];
    float* outp = (float*)d_out;

    char* base = (char*)d_ws;
    size_t off = 0;
    auto alloc = [&](size_t bytes) -> void* {
        void* p = base + off;
        off += (bytes + 255) & ~(size_t)255;
        return p;
    };
    float* frame_x = (float*)alloc(D1 * 4);
    float* role_x  = (float*)alloc(NA * D1 * 4);
    float* part    = (float*)alloc((size_t)8 * AGG_NB * 3 * D1 * 4);
    float* kf   = (float*)alloc(64 * 4);
    float* vf   = (float*)alloc(64 * 4);
    float* kr   = (float*)alloc(512 * 4);
    float* qr   = (float*)alloc(512 * 4);
    float* vr   = (float*)alloc(512 * 4);
    float* outf = (float*)alloc(64 * 4);
    float* outr = (float*)alloc(512 * 4);
    float* flog = (float*)alloc(NFR * 4);
    int* row_ptr  = (int*)alloc((NN + 1) * 4);
    // ---- zero region: cursor | masks | hist ----
    int* cursor   = (int*)alloc(NN * 4);
    unsigned* maskA = (unsigned*)alloc(NN * 4);
    unsigned* maskB = (unsigned*)alloc(NN * 4);
    unsigned* maskC = (unsigned*)alloc(NN * 4);
    unsigned* hist  = (unsigned*)alloc(9 * 64 * 4);
    size_t zero_end = off;
    size_t zero_beg = (char*)cursor - base;
    int* csr_pack = (int*)alloc((size_t)NE * 4);
    unsigned short* xl    = (unsigned short*)alloc((size_t)NN * D1 * 2);
    unsigned short* xr_   = (unsigned short*)alloc((size_t)NN * D1 * 2);
    unsigned short* hbuf  = (unsigned short*)alloc((size_t)NN * D1 * 2);
    unsigned short* hi1   = (unsigned short*)alloc((size_t)NN * D1 * 2);
    unsigned short* hi2   = (unsigned short*)alloc((size_t)NN * D1 * 2);
    unsigned short* hi3   = (unsigned short*)alloc((size_t)NN * D1 * 2);
    unsigned short* pemb  = (unsigned short*)alloc((size_t)NN * EMBD * 2);
    unsigned short* wl1t  = (unsigned short*)alloc((size_t)D1 * EMBD * 2);  // [512][128] BT
    unsigned short* wr1t  = (unsigned short*)alloc((size_t)D1 * EMBD * 2);
    unsigned short* wl2t  = (unsigned short*)alloc((size_t)D1 * D1 * 2);    // [512][512] BT
    unsigned short* wr2t  = (unsigned short*)alloc((size_t)D1 * D1 * 2);
    unsigned short* attr1 = (unsigned short*)alloc((size_t)NATTR * D1 * 2);
    unsigned short* attr2 = (unsigned short*)alloc((size_t)NATTR * D1 * 2);
    unsigned short* mee1  = (unsigned short*)alloc(D1 * 2);
    unsigned short* mee2  = (unsigned short*)alloc((size_t)NA * D1 * 2);

    hipMemsetAsync(base + zero_beg, 0, zero_end - zero_beg, stream);
    k_prep<<<854, 512, 0, stream>>>(pred_emb, We1, We2, node_pred, e_dst, arg_nodes,
                                    attr1, attr2, pemb, cursor, maskA);
    k_transp<<<160, 256, 0, stream>>>(Wl1, Wr1, Wl2, Wr2, wl1t, wr1t, wl2t, wr2t);
    k_scan_g<10><<<1, 1024, 0, stream>>>(cursor, NN, row_ptr, cursor);
    k_scatter<<<256, 256, 0, stream>>>(e_src, e_dst, edge_attr, cursor, csr_pack);

    dim3 gg(D1 / 64, (NN + 63) / 64);
    k_gemm_dual<<<gg, 256, 0, stream>>>(pemb, wl1t, wr1t, xl, xr_, NN, EMBD, D1);

    k_prop<<<256, 256, 0, stream>>>(maskA, maskB, e_src, e_dst);
    k_prop<<<256, 256, 0, stream>>>(maskB, maskC, e_src, e_dst);
    k_prop<<<256, 256, 0, stream>>>(maskC, maskA, e_src, e_dst);

    k_hist<<<256, 256, 0, stream>>>(e_src, e_dst, edge_attr, maskA, hist);
    k_mean_ee<<<9, 512, 0, stream>>>(hist, pred_emb, We1, We2, mee1, mee2);

    k_gat<<<NN, 256, 0, stream>>>(xl, xr_, attr1, mee1, att1, b1,
                                  row_ptr, csr_pack, hbuf);
    k_aggr_partial<<<AGG_NB, 512, 0, stream>>>(hbuf, part);
    k_combine_w<<<64, 512, 0, stream>>>(part, AGG_NB, 1, frame_x);

    k_gemm_dual<<<gg, 256, 0, stream>>>(hbuf, wl2t, wr2t, xl, xr_, NN, D1, D1);

    for (int pb = 0; pb < 2; ++pb) {
        int bb = pb * 4;
        k_gat_m4<<<NN, 256, 0, stream>>>(xl, xr_, attr2, mee2 + (size_t)bb * D1, att2, b2,
                                         row_ptr, csr_pack, maskA, bb,
                                         hbuf, hi1, hi2, hi3);
        k_aggr_partial4<<<AGG_NB, 512, 0, stream>>>(hbuf, hi1, hi2, hi3, maskA, bb,
                                                    part + (size_t)pb * 4 * AGG_NB * 3 * D1);
    }
    k_combine_w<<<512, 512, 0, stream>>>(part, AGG_NB, 8, role_x);

    k_hgt_a<<<26, 64, 0, stream>>>(frame_x, role_x, kqv_f, kqvb_f, kqv_r, kqvb_r,
                                   kf, vf, kr, qr, vr);
    k_hgt_b<<<1, 512, 0, stream>>>(kf, vf, kr, qr, vr, a_rel, m_rel, p_rel,
                                   aW_f, ab_f, aW_r, ab_r, outf, outr);
    k_frame_logits<<<(NFR + 255) / 256, 256, 0, stream>>>(outf, Wfr, bfr, flog);
    k_final<<<1, 512, 0, stream>>>(flog, outr, Wro, bro, outp);
}

// Round 13
// 342.952 us; speedup vs baseline: 1.1173x; 1.1173x over previous
//
#include <hip/hip_runtime.h>
#include <cfloat>
#include <cmath>

static constexpr int NN   = 10000;
static constexpr int NE   = 160000;
static constexpr int NA   = 8;
static constexpr int D1   = 512;
static constexpr int EMBD = 128;
static constexpr int NATTR= 64;
static constexpr int OUTD = 64;
static constexpr int NFR  = 1500;
static constexpr int AGG_NB = 250;

typedef short bf16x8 __attribute__((ext_vector_type(8)));
typedef float f32x4  __attribute__((ext_vector_type(4)));

__device__ __forceinline__ float b2f(unsigned short u) {
    union { unsigned u; float f; } v; v.u = ((unsigned)u) << 16; return v.f;
}
__device__ __forceinline__ unsigned short f2b(float f) {
    union { float f; unsigned u; } v; v.f = f;
    unsigned r = v.u + 0x7FFFu + ((v.u >> 16) & 1u);
    return (unsigned short)(r >> 16);
}
__device__ __forceinline__ float lrelu(float z) { return (z > 0.f) ? z : 0.2f * z; }

__device__ __forceinline__ void async16(unsigned short* lds, const unsigned short* g) {
    __builtin_amdgcn_global_load_lds(
        (const __attribute__((address_space(1))) void*)g,
        (__attribute__((address_space(3))) void*)lds,
        16, 0, 0);
}

// ================= fused prep: attr_ee | gather | indeg | seed =================
__global__ __launch_bounds__(512) void k_prep(const float* __restrict__ pred_emb,
                                              const float* __restrict__ We1,
                                              const float* __restrict__ We2,
                                              const int* __restrict__ node_pred,
                                              const int* __restrict__ e_dst,
                                              const int* __restrict__ arg_nodes,
                                              unsigned short* __restrict__ attr1,
                                              unsigned short* __restrict__ attr2,
                                              unsigned short* __restrict__ pemb,
                                              int* __restrict__ counts,
                                              unsigned* __restrict__ maskA) {
    int b = blockIdx.x, t = threadIdx.x;
    if (b < 128) {                       // attr tables
        int a = b & 63;
        const float* We = (b >> 6) ? We2 : We1;
        unsigned short* out = (b >> 6) ? attr2 : attr1;
        __shared__ float row[EMBD];
        if (t < EMBD) row[t] = pred_emb[a * EMBD + t];
        __syncthreads();
        float acc = 0.f;
        for (int k = 0; k < EMBD; ++k) acc += row[k] * We[k * D1 + t];
        out[a * D1 + t] = f2b(acc);
    } else if (b < 753) {                // gather pemb (320000 float4)
        int idx = (b - 128) * 512 + t;
        int n = idx >> 5, j = idx & 31;
        float4 v = ((const float4*)(pred_emb + (size_t)node_pred[n] * EMBD))[j];
        ushort4 o; o.x = f2b(v.x); o.y = f2b(v.y); o.z = f2b(v.z); o.w = f2b(v.w);
        ((ushort4*)(pemb + (size_t)n * EMBD))[j] = o;
    } else if (b < 853) {                // in-degree
        int id = (b - 753) * 512 + t;
        for (int e = id; e < NE; e += 100 * 512) atomicAdd(&counts[e_dst[e]], 1);
    } else {                             // seed masks
        if (t < NA) atomicOr(&maskA[arg_nodes[t]], 1u << t);
    }
}

// ================= transpose+cast the 4 weight matrices (out: [N][K] bf16) =================
__global__ __launch_bounds__(256) void k_transp(const float* __restrict__ W1, const float* __restrict__ W2,
                                                const float* __restrict__ W3, const float* __restrict__ W4,
                                                unsigned short* __restrict__ o1, unsigned short* __restrict__ o2,
                                                unsigned short* __restrict__ o3, unsigned short* __restrict__ o4) {
    int b = blockIdx.x;
    const float* W; unsigned short* out; int Kd, tile;
    if (b < 16)      { W = W1; out = o1; Kd = 128; tile = b; }
    else if (b < 32) { W = W2; out = o2; Kd = 128; tile = b - 16; }
    else if (b < 96) { W = W3; out = o3; Kd = 512; tile = b - 32; }
    else             { W = W4; out = o4; Kd = 512; tile = b - 96; }
    int nrt = Kd / 64;
    int rt = tile % nrt, ct = tile / nrt;
    int r0 = rt * 64, c0 = ct * 64;
    __shared__ float tl[64][65];
    int tid = threadIdx.x;
#pragma unroll
    for (int i = 0; i < 16; ++i) {
        int idx = tid + 256 * i;
        int row = idx >> 6, col = idx & 63;
        tl[row][col] = W[(size_t)(r0 + row) * D1 + c0 + col];
    }
    __syncthreads();
#pragma unroll
    for (int i = 0; i < 16; ++i) {
        int idx = tid + 256 * i;
        int orow = idx >> 6, ocol = idx & 63;
        out[(size_t)(c0 + orow) * Kd + r0 + ocol] = f2b(tl[ocol][orow]);
    }
}

// ================= generic single-block scan (2 barriers) =================
template <int CE>
__global__ __launch_bounds__(1024) void k_scan_g(const int* __restrict__ counts, int n,
                                                 int* __restrict__ row_ptr,
                                                 int* __restrict__ cursor) {
    __shared__ int wsum[16];
    __shared__ int total_s;
    int t = threadIdx.x, lane = t & 63, w = t >> 6;
    int base = t * CE;
    int v[CE];
    int s = 0;
#pragma unroll
    for (int j = 0; j < CE; ++j) {
        int idx = base + j;
        int x = (idx < n) ? counts[idx] : 0;
        v[j] = s; s += x;
    }
    int inc = s;
#pragma unroll
    for (int off = 1; off < 64; off <<= 1) {
        int u = __shfl_up(inc, off, 64);
        if (lane >= off) inc += u;
    }
    if (lane == 63) wsum[w] = inc;
    __syncthreads();
    if (w == 0 && lane < 16) {
        int ws = wsum[lane];
        int wi = ws;
#pragma unroll
        for (int off = 1; off < 16; off <<= 1) {
            int u = __shfl_up(wi, off, 64);
            if (lane >= off) wi += u;
        }
        wsum[lane] = wi - ws;
        if (lane == 15) total_s = wi;
    }
    __syncthreads();
    int excl = wsum[w] + (inc - s);
#pragma unroll
    for (int j = 0; j < CE; ++j) {
        int idx = base + j;
        if (idx < n) { int val = excl + v[j]; row_ptr[idx] = val; cursor[idx] = val; }
    }
    if (t == 0) row_ptr[n] = total_s;
}

// ================= scatter main CSR (packed src|attr<<14) =================
__global__ void k_scatter(const int* __restrict__ src, const int* __restrict__ dst,
                          const int* __restrict__ attr, int* __restrict__ cursor,
                          int* __restrict__ csr_pack) {
    int stride = gridDim.x * blockDim.x;
    for (int e = blockIdx.x * blockDim.x + threadIdx.x; e < NE; e += stride) {
        int pos = atomicAdd(&cursor[dst[e]], 1);
        csr_pack[pos] = src[e] | ((attr[e] & 63) << 14);
    }
}

// ================= k-hop propagation =================
__global__ void k_prop(const unsigned* __restrict__ oldm, unsigned* __restrict__ newm,
                       const int* __restrict__ src, const int* __restrict__ dst) {
    int stride = gridDim.x * blockDim.x;
    int t0 = blockIdx.x * blockDim.x + threadIdx.x;
    for (int n = t0; n < NN; n += stride) atomicOr(&newm[n], oldm[n]);
    for (int e = t0; e < NE; e += stride) {
        unsigned v = oldm[dst[e]];
        if (v) atomicOr(&newm[src[e]], v);
    }
}

// ================= attr histogram =================
__global__ void k_hist(const int* __restrict__ src, const int* __restrict__ dst,
                       const int* __restrict__ attr, const unsigned* __restrict__ mask,
                       unsigned* __restrict__ hist) {
    __shared__ unsigned lh[9 * 64];
    for (int i = threadIdx.x; i < 9 * 64; i += blockDim.x) lh[i] = 0;
    __syncthreads();
    int stride = gridDim.x * blockDim.x;
    for (int e = blockIdx.x * blockDim.x + threadIdx.x; e < NE; e += stride) {
        int a = attr[e] & 63;
        atomicAdd(&lh[a], 1u);
        unsigned bits = mask[src[e]] & mask[dst[e]];
        while (bits) {
            int i = __ffs(bits) - 1;
            bits &= bits - 1;
            atomicAdd(&lh[(1 + i) * 64 + a], 1u);
        }
    }
    __syncthreads();
    for (int i = threadIdx.x; i < 9 * 64; i += blockDim.x)
        if (lh[i]) atomicAdd(&hist[i], lh[i]);
}

// ================= mean edge embedding tables =================
__global__ __launch_bounds__(512) void k_mean_ee(const unsigned* __restrict__ hist,
                                                 const float* __restrict__ pred_emb,
                                                 const float* __restrict__ We1,
                                                 const float* __restrict__ We2,
                                                 unsigned short* __restrict__ mee1,
                                                 unsigned short* __restrict__ mee2) {
    int g = blockIdx.x;
    const float* We = (g == 0) ? We1 : We2;
    unsigned short* out = (g == 0) ? mee1 : (mee2 + (g - 1) * D1);
    __shared__ float cnt[64];
    __shared__ float me[EMBD];
    __shared__ float tot_s;
    if (threadIdx.x < 64) cnt[threadIdx.x] = (float)hist[g * 64 + threadIdx.x];
    __syncthreads();
    if (threadIdx.x == 0) {
        float tt = 0.f;
        for (int a = 0; a < 64; ++a) tt += cnt[a];
        tot_s = fmaxf(tt, 1.0f);
    }
    __syncthreads();
    if (threadIdx.x < EMBD) {
        float acc = 0.f;
        for (int a = 0; a < 64; ++a) acc += cnt[a] * pred_emb[a * EMBD + threadIdx.x];
        me[threadIdx.x] = acc / tot_s;
    }
    __syncthreads();
    int c = threadIdx.x;
    float acc = 0.f;
    for (int k = 0; k < EMBD; ++k) acc += me[k] * We[k * D1 + c];
    out[c] = f2b(acc);
}

// ===== fused dual-B bf16 MFMA GEMM: async gload_lds staging (source-swizzled, linear LDS) =====
__global__ __launch_bounds__(256) void k_gemm_dual(const unsigned short* __restrict__ A,
                                                   const unsigned short* __restrict__ BT0,
                                                   const unsigned short* __restrict__ BT1,
                                                   unsigned short* __restrict__ C0,
                                                   unsigned short* __restrict__ C1,
                                                   int M, int K, int N) {
    __shared__ unsigned short As[64 * 64];
    __shared__ unsigned short Bs0[64 * 64];
    __shared__ unsigned short Bs1[64 * 64];
    int tid = threadIdx.x;
    int wave = tid >> 6, lane = tid & 63;
    int bm = blockIdx.y * 64, bn = blockIdx.x * 64;
    int wr = (wave >> 1) * 32, wc = (wave & 1) * 32;
    int r = lane & 15, s8 = (lane >> 4) * 8;
    int rx = (r & 7) << 3;
    f32x4 zero = {0.f, 0.f, 0.f, 0.f};
    f32x4 acc0[2][2] = {{zero, zero}, {zero, zero}};
    f32x4 acc1[2][2] = {{zero, zero}, {zero, zero}};
    // staging geometry: idx = tid + 256*i; row = idx>>3, blk = idx&7 (16B blocks);
    // LDS linear at idx*8 ushorts == wave_base + lane*8; source col pre-swizzled blk^(row&7).
    for (int k0 = 0; k0 < K; k0 += 64) {
#pragma unroll
        for (int i = 0; i < 2; ++i) {
            int idx = tid + 256 * i;
            int row = idx >> 3, blk = idx & 7;
            int sb = (blk ^ (row & 7)) * 8;
            int ldsoff = (wave * 64 + i * 256) * 8;    // wave-uniform base (ushorts)
            int rA = bm + row; if (rA >= M) rA = M - 1;
            async16(&As[ldsoff],  &A[(size_t)rA * K + k0 + sb]);
            async16(&Bs0[ldsoff], &BT0[(size_t)(bn + row) * K + k0 + sb]);
            async16(&Bs1[ldsoff], &BT1[(size_t)(bn + row) * K + k0 + sb]);
        }
        __syncthreads();
#pragma unroll
        for (int kk = 0; kk < 2; ++kk) {
            int csw = (kk * 32 + s8) ^ rx;
            bf16x8 a0 = *(const bf16x8*)&As[(wr + r) * 64 + csw];
            bf16x8 a1 = *(const bf16x8*)&As[(wr + 16 + r) * 64 + csw];
            bf16x8 p0 = *(const bf16x8*)&Bs0[(wc + r) * 64 + csw];
            bf16x8 p1 = *(const bf16x8*)&Bs0[(wc + 16 + r) * 64 + csw];
            bf16x8 q0 = *(const bf16x8*)&Bs1[(wc + r) * 64 + csw];
            bf16x8 q1 = *(const bf16x8*)&Bs1[(wc + 16 + r) * 64 + csw];
            acc0[0][0] = __builtin_amdgcn_mfma_f32_16x16x32_bf16(a0, p0, acc0[0][0], 0, 0, 0);
            acc0[0][1] = __builtin_amdgcn_mfma_f32_16x16x32_bf16(a0, p1, acc0[0][1], 0, 0, 0);
            acc0[1][0] = __builtin_amdgcn_mfma_f32_16x16x32_bf16(a1, p0, acc0[1][0], 0, 0, 0);
            acc0[1][1] = __builtin_amdgcn_mfma_f32_16x16x32_bf16(a1, p1, acc0[1][1], 0, 0, 0);
            acc1[0][0] = __builtin_amdgcn_mfma_f32_16x16x32_bf16(a0, q0, acc1[0][0], 0, 0, 0);
            acc1[0][1] = __builtin_amdgcn_mfma_f32_16x16x32_bf16(a0, q1, acc1[0][1], 0, 0, 0);
            acc1[1][0] = __builtin_amdgcn_mfma_f32_16x16x32_bf16(a1, q0, acc1[1][0], 0, 0, 0);
            acc1[1][1] = __builtin_amdgcn_mfma_f32_16x16x32_bf16(a1, q1, acc1[1][1], 0, 0, 0);
        }
        __syncthreads();
    }
    int cr = (lane >> 4) * 4, cc = lane & 15;
#pragma unroll
    for (int i = 0; i < 2; ++i)
#pragma unroll
        for (int j = 0; j < 2; ++j)
#pragma unroll
            for (int q = 0; q < 4; ++q) {
                int row = bm + wr + i * 16 + cr + q;
                int col = bn + wc + j * 16 + cc;
                if (row < M) {
                    C0[(size_t)row * N + col] = f2b(acc0[i][j][q]);
                    C1[(size_t)row * N + col] = f2b(acc1[i][j][q]);
                }
            }
}

// ===== full GATv2: 16-lane groups, 8ch/lane via uint4, 4 edges/wave-iter =====
__global__ __launch_bounds__(256) void k_gat(const unsigned short* __restrict__ xl,
                                             const unsigned short* __restrict__ xr,
                                             const unsigned short* __restrict__ attr_ee,
                                             const unsigned short* __restrict__ mean_ee,
                                             const float* __restrict__ att,
                                             const float* __restrict__ bias,
                                             const int* __restrict__ row_ptr,
                                             const int* __restrict__ csr_pack,
                                             unsigned short* __restrict__ out) {
    int n = blockIdx.x;
    int t = threadIdx.x;
    int lane = t & 63;
    int g = lane >> 4;
    int li = lane & 15;
    int c = (t >> 6) * 128 + li * 8;
    uint4 vr4 = *(const uint4*)&xr[(size_t)n * D1 + c];
    float xrv[8];
    { unsigned w0 = vr4.x, w1 = vr4.y, w2 = vr4.z, w3 = vr4.w;
      xrv[0] = b2f((unsigned short)(w0 & 0xffff)); xrv[1] = b2f((unsigned short)(w0 >> 16));
      xrv[2] = b2f((unsigned short)(w1 & 0xffff)); xrv[3] = b2f((unsigned short)(w1 >> 16));
      xrv[4] = b2f((unsigned short)(w2 & 0xffff)); xrv[5] = b2f((unsigned short)(w2 >> 16));
      xrv[6] = b2f((unsigned short)(w3 & 0xffff)); xrv[7] = b2f((unsigned short)(w3 >> 16)); }
    float4 aLo = *(const float4*)&att[c];
    float4 aHi = *(const float4*)&att[c + 4];
    float av[8] = {aLo.x, aLo.y, aLo.z, aLo.w, aHi.x, aHi.y, aHi.z, aHi.w};
    float m = -FLT_MAX, den = 0.f;
    float ac[8] = {0.f, 0.f, 0.f, 0.f, 0.f, 0.f, 0.f, 0.f};
    int pstart = row_ptr[n], pend = row_ptr[n + 1];
    int deg = pend - pstart;
    int items = deg + 1;
    for (int it = 0; it < items; it += 4) {
        int idx = it + g;
        bool valid = idx < items;
        int s; const unsigned short* ee;
        if (!valid || idx == deg) { s = n; ee = mean_ee; }
        else {
            int v = csr_pack[pstart + idx];
            s = v & 0x3FFF;
            ee = attr_ee + (size_t)((v >> 14) & 63) * D1;
        }
        uint4 vs = *(const uint4*)&xl[(size_t)s * D1 + c];
        uint4 ve = *(const uint4*)&ee[c];
        float x[8];
        x[0] = b2f((unsigned short)(vs.x & 0xffff)); x[1] = b2f((unsigned short)(vs.x >> 16));
        x[2] = b2f((unsigned short)(vs.y & 0xffff)); x[3] = b2f((unsigned short)(vs.y >> 16));
        x[4] = b2f((unsigned short)(vs.z & 0xffff)); x[5] = b2f((unsigned short)(vs.z >> 16));
        x[6] = b2f((unsigned short)(vs.w & 0xffff)); x[7] = b2f((unsigned short)(vs.w >> 16));
        float e[8];
        e[0] = b2f((unsigned short)(ve.x & 0xffff)); e[1] = b2f((unsigned short)(ve.x >> 16));
        e[2] = b2f((unsigned short)(ve.y & 0xffff)); e[3] = b2f((unsigned short)(ve.y >> 16));
        e[4] = b2f((unsigned short)(ve.z & 0xffff)); e[5] = b2f((unsigned short)(ve.z >> 16));
        e[6] = b2f((unsigned short)(ve.w & 0xffff)); e[7] = b2f((unsigned short)(ve.w >> 16));
        float ps = 0.f;
#pragma unroll
        for (int j = 0; j < 8; ++j) ps += lrelu(x[j] + xrv[j] + e[j]) * av[j];
#pragma unroll
        for (int off = 1; off < 16; off <<= 1) ps += __shfl_xor(ps, off, 64);
        if (!valid) ps = -FLT_MAX;
        float nm = fmaxf(m, ps);
        float sc = __expf(m - nm);
        float w  = __expf(ps - nm);
        den = den * sc + w;
#pragma unroll
        for (int j = 0; j < 8; ++j) ac[j] = ac[j] * sc + w * x[j];
        m = nm;
    }
#pragma unroll
    for (int off = 16; off <= 32; off <<= 1) {
        float mO = __shfl_xor(m, off, 64);
        float dO = __shfl_xor(den, off, 64);
        float aO[8];
#pragma unroll
        for (int j = 0; j < 8; ++j) aO[j] = __shfl_xor(ac[j], off, 64);
        float nm = fmaxf(m, mO);
        float sa = __expf(m - nm), sb = __expf(mO - nm);
        den = den * sa + dO * sb;
#pragma unroll
        for (int j = 0; j < 8; ++j) ac[j] = ac[j] * sa + aO[j] * sb;
        m = nm;
    }
    if (g == 0) {
        float inv = 1.f / (den + 1e-16f);
        float4 bLo = *(const float4*)&bias[c];
        float4 bHi = *(const float4*)&bias[c + 4];
        float bv[8] = {bLo.x, bLo.y, bLo.z, bLo.w, bHi.x, bHi.y, bHi.z, bHi.w};
        unsigned short q[8];
#pragma unroll
        for (int j = 0; j < 8; ++j) q[j] = f2b(ac[j] * inv + bv[j]);
        uint4 o;
        o.x = ((unsigned)q[1] << 16) | q[0];
        o.y = ((unsigned)q[3] << 16) | q[2];
        o.z = ((unsigned)q[5] << 16) | q[4];
        o.w = ((unsigned)q[7] << 16) | q[6];
        *(uint4*)&out[(size_t)n * D1 + c] = o;
    }
}

// ================= merged 4-bit masked GATv2 (ballot compaction) =================
__global__ __launch_bounds__(256) void k_gat_m4(const unsigned short* __restrict__ xl,
                                                const unsigned short* __restrict__ xr,
                                                const unsigned short* __restrict__ attr_ee,
                                                const unsigned short* __restrict__ mee,
                                                const float* __restrict__ att,
                                                const float* __restrict__ bias,
                                                const int* __restrict__ row_ptr,
                                                const int* __restrict__ csr_pack,
                                                const unsigned* __restrict__ mask, int bitbase,
                                                unsigned short* __restrict__ o0,
                                                unsigned short* __restrict__ o1,
                                                unsigned short* __restrict__ o2,
                                                unsigned short* __restrict__ o3) {
    int n = blockIdx.x;
    unsigned mb_n = (mask[n] >> bitbase) & 0xFu;
    if (!mb_n) return;
    __shared__ int lst[256];
    __shared__ int lcnt;
    int t = threadIdx.x, lane = t & 63;
    int c = 2 * t;
    unsigned vr_ = *(const unsigned*)&xr[(size_t)n * D1 + c];
    float xr0 = b2f((unsigned short)(vr_ & 0xffff));
    float xr1 = b2f((unsigned short)(vr_ >> 16));
    float a0 = att[c], a1 = att[c + 1];
    float m[4], den[4], ac0[4], ac1[4];
#pragma unroll
    for (int b = 0; b < 4; ++b) { m[b] = -FLT_MAX; den[b] = 0.f; ac0[b] = 0.f; ac1[b] = 0.f; }
    int pstart = row_ptr[n], pend = row_ptr[n + 1];
    for (int p0 = pstart; p0 < pend; p0 += 256) {
        int chunk = min(256, pend - p0);
        __syncthreads();
        if (t == 0) lcnt = 0;
        __syncthreads();
        unsigned bits = 0; int pk = 0;
        if (t < chunk) {
            pk = csr_pack[p0 + t];
            bits = (mask[pk & 0x3FFF] >> bitbase) & mb_n & 0xFu;
        }
        bool kept = bits != 0;
        unsigned long long bal = __ballot(kept);
        int base = 0;
        if (lane == 0) base = atomicAdd(&lcnt, __popcll(bal));
        base = __shfl(base, 0, 64);
        int pfx = __popcll(bal & ((1ull << lane) - 1));
        if (kept) lst[base + pfx] = (pk & 0xFFFFF) | ((int)bits << 20);
        __syncthreads();
        int cnt = lcnt;
        int i = 0;
        for (; i + 1 < cnt; i += 2) {
            int vA = lst[i], vB = lst[i + 1];
            int sA = vA & 0x3FFF, sB = vB & 0x3FFF;
            unsigned bA = ((unsigned)vA >> 20) & 0xF, bB = ((unsigned)vB >> 20) & 0xF;
            const unsigned short* eA = attr_ee + (size_t)((vA >> 14) & 63) * D1;
            const unsigned short* eB = attr_ee + (size_t)((vB >> 14) & 63) * D1;
            unsigned vsA = *(const unsigned*)&xl[(size_t)sA * D1 + c];
            unsigned veA = *(const unsigned*)&eA[c];
            unsigned vsB = *(const unsigned*)&xl[(size_t)sB * D1 + c];
            unsigned veB = *(const unsigned*)&eB[c];
            float xA0 = b2f((unsigned short)(vsA & 0xffff)), xA1 = b2f((unsigned short)(vsA >> 16));
            float xB0 = b2f((unsigned short)(vsB & 0xffff)), xB1 = b2f((unsigned short)(vsB >> 16));
            float zA0 = lrelu(xA0 + xr0 + b2f((unsigned short)(veA & 0xffff)));
            float zA1 = lrelu(xA1 + xr1 + b2f((unsigned short)(veA >> 16)));
            float zB0 = lrelu(xB0 + xr0 + b2f((unsigned short)(veB & 0xffff)));
            float zB1 = lrelu(xB1 + xr1 + b2f((unsigned short)(veB >> 16)));
            float pa = zA0 * a0 + zA1 * a1;
            float pb = zB0 * a0 + zB1 * a1;
#pragma unroll
            for (int off = 32; off; off >>= 1) {
                pa += __shfl_xor(pa, off, 64);
                pb += __shfl_xor(pb, off, 64);
            }
#pragma unroll
            for (int b = 0; b < 4; ++b) {
                if (!(((bA | bB) >> b) & 1)) continue;   // wave-uniform
                float pae = ((bA >> b) & 1) ? pa : -FLT_MAX;
                float pbe = ((bB >> b) & 1) ? pb : -FLT_MAX;
                float nm = fmaxf(m[b], fmaxf(pae, pbe));
                float sc = __expf(m[b] - nm);
                float wa = __expf(pae - nm);
                float wb = __expf(pbe - nm);
                den[b] = den[b] * sc + wa + wb;
                ac0[b] = ac0[b] * sc + wa * xA0 + wb * xB0;
                ac1[b] = ac1[b] * sc + wa * xA1 + wb * xB1;
                m[b] = nm;
            }
        }
        if (i < cnt) {
            int vA = lst[i];
            int sA = vA & 0x3FFF;
            unsigned bA = ((unsigned)vA >> 20) & 0xF;
            const unsigned short* eA = attr_ee + (size_t)((vA >> 14) & 63) * D1;
            unsigned vsA = *(const unsigned*)&xl[(size_t)sA * D1 + c];
            unsigned veA = *(const unsigned*)&eA[c];
            float xA0 = b2f((unsigned short)(vsA & 0xffff)), xA1 = b2f((unsigned short)(vsA >> 16));
            float zA0 = lrelu(xA0 + xr0 + b2f((unsigned short)(veA & 0xffff)));
            float zA1 = lrelu(xA1 + xr1 + b2f((unsigned short)(veA >> 16)));
            float pa = zA0 * a0 + zA1 * a1;
#pragma unroll
            for (int off = 32; off; off >>= 1) pa += __shfl_xor(pa, off, 64);
#pragma unroll
            for (int b = 0; b < 4; ++b) {
                if (!((bA >> b) & 1)) continue;
                float nm = fmaxf(m[b], pa);
                float sc = __expf(m[b] - nm);
                float wa = __expf(pa - nm);
                den[b] = den[b] * sc + wa;
                ac0[b] = ac0[b] * sc + wa * xA0;
                ac1[b] = ac1[b] * sc + wa * xA1;
                m[b] = nm;
            }
        }
    }
    unsigned vsn = *(const unsigned*)&xl[(size_t)n * D1 + c];
    float xn0 = b2f((unsigned short)(vsn & 0xffff)), xn1 = b2f((unsigned short)(vsn >> 16));
    float bi0 = bias[c], bi1 = bias[c + 1];
#pragma unroll
    for (int b = 0; b < 4; ++b) {
        if (!((mb_n >> b) & 1)) continue;
        unsigned ve = *(const unsigned*)&mee[(size_t)b * D1 + c];
        float z0 = lrelu(xn0 + xr0 + b2f((unsigned short)(ve & 0xffff)));
        float z1 = lrelu(xn1 + xr1 + b2f((unsigned short)(ve >> 16)));
        float ps = z0 * a0 + z1 * a1;
#pragma unroll
        for (int off = 32; off; off >>= 1) ps += __shfl_xor(ps, off, 64);
        float nm = fmaxf(m[b], ps);
        float sc = __expf(m[b] - nm);
        float w  = __expf(ps - nm);
        float dd = den[b] * sc + w;
        float A0 = ac0[b] * sc + w * xn0;
        float A1 = ac1[b] * sc + w * xn1;
        float inv = 1.f / (dd + 1e-16f);
        unsigned short q0 = f2b(A0 * inv + bi0);
        unsigned short q1 = f2b(A1 * inv + bi1);
        unsigned pkd = ((unsigned)q1 << 16) | q0;
        unsigned short* ob = (b == 0) ? o0 : (b == 1) ? o1 : (b == 2) ? o2 : o3;
        *(unsigned*)&ob[(size_t)n * D1 + c] = pkd;
    }
}

// ================= full column softmax-aggr partial (quad-ILP) =================
__global__ __launch_bounds__(512) void k_aggr_partial(const unsigned short* __restrict__ x,
                                                      float* __restrict__ part) {
    int c = threadIdx.x;
    int rows = NN / gridDim.x;
    int r0 = blockIdx.x * rows;
    int r1 = r0 + rows;
    float m = -FLT_MAX, den = 0.f, num = 0.f;
    for (int r = r0; r < r1; r += 4) {
        float v0 = b2f(x[(size_t)r * D1 + c]);
        float v1 = b2f(x[(size_t)(r + 1) * D1 + c]);
        float v2 = b2f(x[(size_t)(r + 2) * D1 + c]);
        float v3 = b2f(x[(size_t)(r + 3) * D1 + c]);
        float nm = fmaxf(fmaxf(fmaxf(v0, v1), fmaxf(v2, v3)), m);
        float sc = __expf(m - nm);
        float w0 = __expf(v0 - nm);
        float w1 = __expf(v1 - nm);
        float w2 = __expf(v2 - nm);
        float w3 = __expf(v3 - nm);
        den = den * sc + ((w0 + w1) + (w2 + w3));
        num = num * sc + ((w0 * v0 + w1 * v1) + (w2 * v2 + w3 * v3));
        m = nm;
    }
    part[(blockIdx.x * 3 + 0) * D1 + c] = m;
    part[(blockIdx.x * 3 + 1) * D1 + c] = den;
    part[(blockIdx.x * 3 + 2) * D1 + c] = num;
}

// ================= merged 4-bit masked softmax-aggr partial =================
__global__ __launch_bounds__(512) void k_aggr_partial4(const unsigned short* __restrict__ h0,
                                                       const unsigned short* __restrict__ h1,
                                                       const unsigned short* __restrict__ h2,
                                                       const unsigned short* __restrict__ h3,
                                                       const unsigned* __restrict__ mask, int bitbase,
                                                       float* __restrict__ part) {
    int c = threadIdx.x;
    int rows = NN / gridDim.x;
    int r0 = blockIdx.x * rows;
    int r1 = r0 + rows;
    float m[4], den[4], num[4];
#pragma unroll
    for (int b = 0; b < 4; ++b) { m[b] = -FLT_MAX; den[b] = 0.f; num[b] = 0.f; }
    for (int r = r0; r < r1; ++r) {
        unsigned bits = (mask[r] >> bitbase) & 0xFu;
        if (!bits) continue;
#pragma unroll
        for (int b = 0; b < 4; ++b) {
            if (!((bits >> b) & 1)) continue;
            const unsigned short* hb = (b == 0) ? h0 : (b == 1) ? h1 : (b == 2) ? h2 : h3;
            float v = b2f(hb[(size_t)r * D1 + c]);
            float nm = fmaxf(m[b], v);
            float sc = __expf(m[b] - nm);
            float w  = __expf(v - nm);
            den[b] = den[b] * sc + w;
            num[b] = num[b] * sc + w * v;
            m[b] = nm;
        }
    }
#pragma unroll
    for (int b = 0; b < 4; ++b) {
        part[(((size_t)b * gridDim.x + blockIdx.x) * 3 + 0) * D1 + c] = m[b];
        part[(((size_t)b * gridDim.x + blockIdx.x) * 3 + 1) * D1 + c] = den[b];
        part[(((size_t)b * gridDim.x + blockIdx.x) * 3 + 2) * D1 + c] = num[b];
    }
}

// ================= wave-parallel combine =================
__global__ __launch_bounds__(512) void k_combine_w(const float* __restrict__ part,
                                                   int nb, int nset,
                                                   float* __restrict__ out) {
    int gw = (blockIdx.x * 512 + threadIdx.x) >> 6;
    int lane = threadIdx.x & 63;
    if (gw >= nset * D1) return;
    int s = gw >> 9;
    int c = gw & 511;
    const float* pp = part + (size_t)s * nb * 3 * D1;
    float m = -FLT_MAX;
    for (int k = lane; k < nb; k += 64) m = fmaxf(m, pp[(k * 3) * D1 + c]);
#pragma unroll
    for (int off = 32; off; off >>= 1) m = fmaxf(m, __shfl_xor(m, off, 64));
    float den = 0.f, num = 0.f;
    for (int k = lane; k < nb; k += 64) {
        float sc = __expf(pp[(k * 3 + 0) * D1 + c] - m);
        den += pp[(k * 3 + 1) * D1 + c] * sc;
        num += pp[(k * 3 + 2) * D1 + c] * sc;
    }
#pragma unroll
    for (int off = 32; off; off >>= 1) {
        den += __shfl_xor(den, off, 64);
        num += __shfl_xor(num, off, 64);
    }
    if (lane == 0) out[(size_t)s * D1 + c] = num / den;
}

// ================= HGT stage A =================
__global__ void k_hgt_a(const float* __restrict__ frame_x, const float* __restrict__ role_x,
                        const float* __restrict__ kqv_f, const float* __restrict__ kqvb_f,
                        const float* __restrict__ kqv_r, const float* __restrict__ kqvb_r,
                        float* __restrict__ kf, float* __restrict__ vf,
                        float* __restrict__ kr, float* __restrict__ qr, float* __restrict__ vr) {
    int b = blockIdx.x, j = threadIdx.x;
    const float *x, *W, *bi;
    float* out;
    if (b == 0)      { x = frame_x;               W = kqv_f;                    bi = kqvb_f;            out = kf; }
    else if (b == 1) { x = frame_x;               W = kqv_f + 2 * D1 * OUTD;    bi = kqvb_f + 2 * OUTD; out = vf; }
    else if (b < 10) { int i = b - 2;  x = role_x + i * D1; W = kqv_r;                 bi = kqvb_r;            out = kr + i * OUTD; }
    else if (b < 18) { int i = b - 10; x = role_x + i * D1; W = kqv_r + D1 * OUTD;     bi = kqvb_r + OUTD;     out = qr + i * OUTD; }
    else             { int i = b - 18; x = role_x + i * D1; W = kqv_r + 2 * D1 * OUTD; bi = kqvb_r + 2 * OUTD; out = vr + i * OUTD; }
    float acc = bi[j];
    for (int k = 0; k < D1; ++k) acc += x[k] * W[k * OUTD + j];
    out[j] = acc;
}

// ================= HGT stage B =================
__global__ __launch_bounds__(512) void k_hgt_b(const float* __restrict__ kf_g,
                                               const float* __restrict__ vf_g,
                                               const float* __restrict__ kr_g,
                                               const float* __restrict__ qr_g,
                                               const float* __restrict__ vr_g,
                                               const float* __restrict__ a_rel,
                                               const float* __restrict__ m_rel,
                                               const float* __restrict__ p_rel,
                                               const float* __restrict__ aW_f,
                                               const float* __restrict__ ab_f,
                                               const float* __restrict__ aW_r,
                                               const float* __restrict__ ab_r,
                                               float* __restrict__ out_f,
                                               float* __restrict__ out_r) {
    __shared__ float kf[64], vf[64], kr[512], qr[512], vr[512];
    __shared__ float ka1[64], vfm1[64], aggf[64], geluf[64];
    __shared__ float kra2[512], vrm[512], gelur[512];
    __shared__ float al[8][2];
    int t = threadIdx.x;
    if (t < 64) { kf[t] = kf_g[t]; vf[t] = vf_g[t]; }
    kr[t] = kr_g[t]; qr[t] = qr_g[t]; vr[t] = vr_g[t];
    __syncthreads();
    int i = t >> 6, j = t & 63;
    {
        float acc1 = 0.f, acc2 = 0.f;
        for (int k = 0; k < 64; ++k) {
            acc1 += kr[i * 64 + k] * a_rel[2 * 4096 + k * 64 + j];
            acc2 += vr[i * 64 + k] * m_rel[2 * 4096 + k * 64 + j];
        }
        kra2[t] = acc1; vrm[t] = acc2;
    }
    if (t < 64) {
        float acc1 = 0.f, acc2 = 0.f, acc3 = 0.f;
        for (int k = 0; k < 64; ++k) {
            acc1 += kf[k] * a_rel[1 * 4096 + k * 64 + j];
            acc2 += vf[k] * m_rel[0 * 4096 + k * 64 + j];
            acc3 += vf[k] * m_rel[1 * 4096 + k * 64 + j];
        }
        ka1[j] = acc1; aggf[j] = acc2; vfm1[j] = acc3;
    }
    __syncthreads();
    if (t < 8) {
        const float sq = 0.125f;
        float p1 = p_rel[1], p2 = p_rel[2];
        float sfr = 0.f, srr = 0.f;
        for (int d = 0; d < 64; ++d) {
            sfr += qr[t * 64 + d] * ka1[d];
            srr += qr[t * 64 + d] * kra2[t * 64 + d];
        }
        sfr *= sq * p1; srr *= sq * p2;
        float mx = fmaxf(sfr, srr);
        float e0 = __expf(sfr - mx), e1 = __expf(srr - mx);
        float inv = 1.f / (e0 + e1);
        al[t][0] = e0 * inv; al[t][1] = e1 * inv;
    }
    __syncthreads();
    {
        float av = al[i][0] * vfm1[j] + al[i][1] * vrm[t];
        gelur[t] = 0.5f * av * (1.f + erff(av * 0.70710678118654752f));
    }
    if (t < 64) geluf[t] = 0.5f * aggf[t] * (1.f + erff(aggf[t] * 0.70710678118654752f));
    __syncthreads();
    {
        float acc = ab_r[j];
        for (int k = 0; k < 64; ++k) acc += gelur[i * 64 + k] * aW_r[k * 64 + j];
        out_r[t] = acc;
    }
    if (t < 64) {
        float acc = ab_f[j];
        for (int k = 0; k < 64; ++k) acc += geluf[k] * aW_f[k * 64 + j];
        out_f[j] = acc;
    }
}

// ================= frame logits =================
__global__ void k_frame_logits(const float* __restrict__ out_f, const float* __restrict__ Wfr,
                               const float* __restrict__ bfr, float* __restrict__ flog) {
    __shared__ float xf[64];
    if (threadIdx.x < 64) xf[threadIdx.x] = out_f[threadIdx.x];
    __syncthreads();
    int j = blockIdx.x * blockDim.x + threadIdx.x;
    if (j >= NFR) return;
    float acc = bfr[j];
    for (int k = 0; k < 64; ++k) acc += xf[k] * Wfr[k * NFR + j];
    flog[j] = acc;
}

// ================= final: frame log_softmax + roles head =================
__global__ __launch_bounds__(512) void k_final(const float* __restrict__ flog,
                                               const float* __restrict__ out_r,
                                               const float* __restrict__ Wro,
                                               const float* __restrict__ bro,
                                               float* __restrict__ outp) {
    __shared__ float red[512];
    __shared__ float xr_s[512];
    int t = threadIdx.x;
    int i = t >> 6, j = t & 63;
    xr_s[t] = out_r[t];
    float racc = bro[j];
    for (int k = 0; k < 64; ++k) racc += xr_s[i * 64 + k] * Wro[k * 64 + j];
    float rm = racc;
#pragma unroll
    for (int off = 32; off; off >>= 1) rm = fmaxf(rm, __shfl_xor(rm, off, 64));
    float re = __expf(racc - rm);
    float rs = re;
#pragma unroll
    for (int off = 32; off; off >>= 1) rs += __shfl_xor(rs, off, 64);
    outp[NFR + t] = racc - rm - logf(rs);
    float m = -FLT_MAX;
    for (int q = t; q < NFR; q += 512) m = fmaxf(m, flog[q]);
    red[t] = m; __syncthreads();
    for (int off = 256; off; off >>= 1) { if (t < off) red[t] = fmaxf(red[t], red[t + off]); __syncthreads(); }
    float M = red[0]; __syncthreads();
    float s = 0.f;
    for (int q = t; q < NFR; q += 512) s += __expf(flog[q] - M);
    red[t] = s; __syncthreads();
    for (int off = 256; off; off >>= 1) { if (t < off) red[t] += red[t + off]; __syncthreads(); }
    float lse = M + logf(red[0]);
    for (int q = t; q < NFR; q += 512) outp[q] = flog[q] - lse;
}

// =====================================================================
extern "C" void kernel_launch(void* const* d_in, const int* in_sizes, int n_in,
                              void* d_out, int out_size, void* d_ws, size_t ws_size,
                              hipStream_t stream) {
    const int* node_pred  = (const int*)d_in[0];
    const int* edge_index = (const int*)d_in[1];
    const int* e_src = edge_index;
    const int* e_dst = edge_index + NE;
    const int* edge_attr  = (const int*)d_in[2];
    const int* arg_nodes  = (const int*)d_in[3];
    const float* pred_emb = (const float*)d_in[4];
    const float* Wl1 = (const float*)d_in[5];
    const float* Wr1 = (const float*)d_in[6];
    const float* We1 = (const float*)d_in[7];
    const float* att1 = (const float*)d_in[8];
    const float* b1  = (const float*)d_in[9];
    const float* Wl2 = (const float*)d_in[10];
    const float* Wr2 = (const float*)d_in[11];
    const float* We2 = (const float*)d_in[12];
    const float* att2 = (const float*)d_in[13];
    const float* b2  = (const float*)d_in[14];
    const float* kqv_f  = (const float*)d_in[15];
    const float* kqvb_f = (const float*)d_in[16];
    const float* kqv_r  = (const float*)d_in[17];
    const float* kqvb_r = (const float*)d_in[18];
    const float* a_rel  = (const float*)d_in[19];
    const float* m_rel  = (const float*)d_in[20];
    const float* p_rel  = (const float*)d_in[21];
    const float* aW_f = (const float*)d_in[22];
    const float* ab_f = (const float*)d_in[23];
    const float* aW_r = (const float*)d_in[24];
    const float* ab_r = (const float*)d_in[25];
    const float* Wfr = (const float*)d_in[26];
    const float* bfr = (const float*)d_in[27];
    const float* Wro = (const float*)d_in[28];
    const float* bro = (const float*)d_in[29];
    float* outp = (float*)d_out;

    char* base = (char*)d_ws;
    size_t off = 0;
    auto alloc = [&](size_t bytes) -> void* {
        void* p = base + off;
        off += (bytes + 255) & ~(size_t)255;
        return p;
    };
    float* frame_x = (float*)alloc(D1 * 4);
    float* role_x  = (float*)alloc(NA * D1 * 4);
    float* part    = (float*)alloc((size_t)8 * AGG_NB * 3 * D1 * 4);
    float* kf   = (float*)alloc(64 * 4);
    float* vf   = (float*)alloc(64 * 4);
    float* kr   = (float*)alloc(512 * 4);
    float* qr   = (float*)alloc(512 * 4);
    float* vr   = (float*)alloc(512 * 4);
    float* outf = (float*)alloc(64 * 4);
    float* outr = (float*)alloc(512 * 4);
    float* flog = (float*)alloc(NFR * 4);
    int* row_ptr  = (int*)alloc((NN + 1) * 4);
    // ---- zero region: cursor | masks | hist ----
    int* cursor   = (int*)alloc(NN * 4);
    unsigned* maskA = (unsigned*)alloc(NN * 4);
    unsigned* maskB = (unsigned*)alloc(NN * 4);
    unsigned* maskC = (unsigned*)alloc(NN * 4);
    unsigned* hist  = (unsigned*)alloc(9 * 64 * 4);
    size_t zero_end = off;
    size_t zero_beg = (char*)cursor - base;
    int* csr_pack = (int*)alloc((size_t)NE * 4);
    unsigned short* xl    = (unsigned short*)alloc((size_t)NN * D1 * 2);
    unsigned short* xr_   = (unsigned short*)alloc((size_t)NN * D1 * 2);
    unsigned short* hbuf  = (unsigned short*)alloc((size_t)NN * D1 * 2);
    unsigned short* hi1   = (unsigned short*)alloc((size_t)NN * D1 * 2);
    unsigned short* hi2   = (unsigned short*)alloc((size_t)NN * D1 * 2);
    unsigned short* hi3   = (unsigned short*)alloc((size_t)NN * D1 * 2);
    unsigned short* pemb  = (unsigned short*)alloc((size_t)NN * EMBD * 2);
    unsigned short* wl1t  = (unsigned short*)alloc((size_t)D1 * EMBD * 2);  // [512][128] BT
    unsigned short* wr1t  = (unsigned short*)alloc((size_t)D1 * EMBD * 2);
    unsigned short* wl2t  = (unsigned short*)alloc((size_t)D1 * D1 * 2);    // [512][512] BT
    unsigned short* wr2t  = (unsigned short*)alloc((size_t)D1 * D1 * 2);
    unsigned short* attr1 = (unsigned short*)alloc((size_t)NATTR * D1 * 2);
    unsigned short* attr2 = (unsigned short*)alloc((size_t)NATTR * D1 * 2);
    unsigned short* mee1  = (unsigned short*)alloc(D1 * 2);
    unsigned short* mee2  = (unsigned short*)alloc((size_t)NA * D1 * 2);

    hipMemsetAsync(base + zero_beg, 0, zero_end - zero_beg, stream);
    k_prep<<<854, 512, 0, stream>>>(pred_emb, We1, We2, node_pred, e_dst, arg_nodes,
                                    attr1, attr2, pemb, cursor, maskA);
    k_transp<<<160, 256, 0, stream>>>(Wl1, Wr1, Wl2, Wr2, wl1t, wr1t, wl2t, wr2t);
    k_scan_g<10><<<1, 1024, 0, stream>>>(cursor, NN, row_ptr, cursor);
    k_scatter<<<256, 256, 0, stream>>>(e_src, e_dst, edge_attr, cursor, csr_pack);

    dim3 gg(D1 / 64, (NN + 63) / 64);
    k_gemm_dual<<<gg, 256, 0, stream>>>(pemb, wl1t, wr1t, xl, xr_, NN, EMBD, D1);

    k_prop<<<256, 256, 0, stream>>>(maskA, maskB, e_src, e_dst);
    k_prop<<<256, 256, 0, stream>>>(maskB, maskC, e_src, e_dst);
    k_prop<<<256, 256, 0, stream>>>(maskC, maskA, e_src, e_dst);

    k_hist<<<256, 256, 0, stream>>>(e_src, e_dst, edge_attr, maskA, hist);
    k_mean_ee<<<9, 512, 0, stream>>>(hist, pred_emb, We1, We2, mee1, mee2);

    k_gat<<<NN, 256, 0, stream>>>(xl, xr_, attr1, mee1, att1, b1,
                                  row_ptr, csr_pack, hbuf);
    k_aggr_partial<<<AGG_NB, 512, 0, stream>>>(hbuf, part);
    k_combine_w<<<64, 512, 0, stream>>>(part, AGG_NB, 1, frame_x);

    k_gemm_dual<<<gg, 256, 0, stream>>>(hbuf, wl2t, wr2t, xl, xr_, NN, D1, D1);

    for (int pb = 0; pb < 2; ++pb) {
        int bb = pb * 4;
        k_gat_m4<<<NN, 256, 0, stream>>>(xl, xr_, attr2, mee2 + (size_t)bb * D1, att2, b2,
                                         row_ptr, csr_pack, maskA, bb,
                                         hbuf, hi1, hi2, hi3);
        k_aggr_partial4<<<AGG_NB, 512, 0, stream>>>(hbuf, hi1, hi2, hi3, maskA, bb,
                                                    part + (size_t)pb * 4 * AGG_NB * 3 * D1);
    }
    k_combine_w<<<512, 512, 0, stream>>>(part, AGG_NB, 8, role_x);

    k_hgt_a<<<26, 64, 0, stream>>>(frame_x, role_x, kqv_f, kqvb_f, kqv_r, kqvb_r,
                                   kf, vf, kr, qr, vr);
    k_hgt_b<<<1, 512, 0, stream>>>(kf, vf, kr, qr, vr, a_rel, m_rel, p_rel,
                                   aW_f, ab_f, aW_r, ab_r, outf, outr);
    k_frame_logits<<<(NFR + 255) / 256, 256, 0, stream>>>(outf, Wfr, bfr, flog);
    k_final<<<1, 512, 0, stream>>>(flog, outr, Wro, bro, outp);
}